// Round 4
// baseline (1089.632 us; speedup 1.0000x reference)
//
#include <hip/hip_runtime.h>
#include <hip/hip_bf16.h>

#define H 768
#define MPAD 30080   // 235 * 128

typedef unsigned short ushort_t;
typedef __attribute__((ext_vector_type(8))) short bf16x8;
typedef __attribute__((ext_vector_type(4))) float f32x4;

__device__ __forceinline__ float b2f(ushort_t u) {
    unsigned x = ((unsigned)u) << 16;
    float f; __builtin_memcpy(&f, &x, 4); return f;
}
__device__ __forceinline__ ushort_t f2b(float f) {
    unsigned x; __builtin_memcpy(&x, &f, 4);
    unsigned r = (x + 0x7FFFu + ((x >> 16) & 1u)) >> 16;
    return (ushort_t)r;
}

// ---------------------------------------------------------------- pos emb ---
__global__ void posemb_kernel(const float* __restrict__ wf,
                              const float* __restrict__ bn,
                              float* __restrict__ h,
                              ushort_t* __restrict__ hb, int N) {
    long long idx = (long long)blockIdx.x * blockDim.x + threadIdx.x;
    if (idx >= (long long)N * H) return;
    int n = (int)(idx / H);
    int f = (int)(idx % H);
    int c = f / 192;
    int j = f % 192;
    int k = (j < 96) ? j : j - 96;
    float invf = expf(-((float)(2 * k) / 192.0f) * 9.210340371976184f);
    float v = bn[n * 4 + c] * invf;
    float pe = (j < 96) ? sinf(v) : cosf(v);
    float o = wf[idx] + pe;
    h[idx] = o;
    hb[idx] = f2b(o);
}

// ---------------------------------------------------------------- CSR build --
__global__ void count_kernel(const int* __restrict__ dst, int* __restrict__ counts, int E) {
    int e = blockIdx.x * blockDim.x + threadIdx.x;
    if (e >= E) return;
    atomicAdd(&counts[dst[e]], 1);
}

__global__ void scan_kernel(const int* __restrict__ counts,
                            int* __restrict__ offsets,
                            int* __restrict__ cursor, int n) {
    __shared__ int partial[1024];
    int tid = threadIdx.x;
    int per = (n + 1023) / 1024;
    int base = tid * per;
    int sum = 0;
    for (int i = 0; i < per; ++i) {
        int idx = base + i;
        if (idx < n) sum += counts[idx];
    }
    partial[tid] = sum;
    __syncthreads();
    for (int offs = 1; offs < 1024; offs <<= 1) {
        int v = 0;
        if (tid >= offs) v = partial[tid - offs];
        __syncthreads();
        if (tid >= offs) partial[tid] += v;
        __syncthreads();
    }
    int running = (tid == 0) ? 0 : partial[tid - 1];
    for (int i = 0; i < per; ++i) {
        int idx = base + i;
        if (idx < n) {
            offsets[idx] = running;
            cursor[idx]  = running;
            running += counts[idx];
        }
    }
    if (tid == 0) offsets[n] = partial[1023];
}

__global__ void scatter_kernel(const int* __restrict__ ei, int* __restrict__ cursor,
                               int* __restrict__ src_s, int* __restrict__ dst_s,
                               int* __restrict__ eid_s, int E) {
    int e = blockIdx.x * blockDim.x + threadIdx.x;
    if (e >= E) return;
    int s = ei[e], d = ei[E + e];
    int p = atomicAdd(&cursor[d], 1);
    src_s[p] = s;
    dst_s[p] = d;
    eid_s[p] = e;
}

// ------------------------------------------------------- We_rel precompute ---
__global__ void werel_kernel(const float* __restrict__ rel_table,
                             const float* __restrict__ We,
                             float* __restrict__ werel) {
    int idx = blockIdx.x * blockDim.x + threadIdx.x;
    if (idx >= 2 * 5 * H) return;
    int f = idx % H;
    int r = (idx / H) % 5;
    int l = idx / (5 * H);
    const float* Wep = We + (size_t)l * 23 * H;
    float s = 0.f;
#pragma unroll
    for (int k = 0; k < 16; ++k)
        s = fmaf(rel_table[r * 16 + k], Wep[(size_t)(7 + k) * H + f], s);
    werel[idx] = s;
}

// -------------------------------------------- weight transpose + bf16 cast ---
// WT[l] layout: [1536][768] bf16; rows 0..767 = Wl[l]^T, rows 768..1535 = Wr[l]^T
__global__ __launch_bounds__(256) void transpose_conv_kernel(
    const float* __restrict__ Wl, const float* __restrict__ Wr,
    ushort_t* __restrict__ WT) {
    __shared__ float t[32][33];
    int z = blockIdx.z;                 // 0:Wl0 1:Wl1 2:Wr0 3:Wr1
    const float* src = ((z < 2) ? Wl : Wr) + (size_t)(z & 1) * H * H;
    ushort_t*    dst = WT + (size_t)(z & 1) * 2 * H * H + ((z < 2) ? 0 : (size_t)H * H);
    int k0 = blockIdx.x * 32, n0 = blockIdx.y * 32;
    int tx = threadIdx.x & 31, ty = threadIdx.x >> 5;   // 32 x 8
#pragma unroll
    for (int r = 0; r < 4; ++r)
        t[ty + 8 * r][tx] = src[(size_t)(k0 + ty + 8 * r) * H + n0 + tx];
    __syncthreads();
#pragma unroll
    for (int r = 0; r < 4; ++r)
        dst[(size_t)(n0 + ty + 8 * r) * H + k0 + tx] = f2b(t[tx][ty + 8 * r]);
}

// ------------------------------------------------------------ MFMA GEMM -----
// [xl | xr][M][768] = A[MPAD][768](bf16) @ WT[1536][768]^T + [bl | br]
// m97 structure: 128x128 tile, BK=32, 4 waves x (64x64), global_load_lds w16
__global__ __launch_bounds__(256) void gemm_mfma(
    const ushort_t* __restrict__ A,
    const ushort_t* __restrict__ Bt,   // [1536][768]
    const float* __restrict__ bl, const float* __restrict__ br,
    ushort_t* __restrict__ xl, ushort_t* __restrict__ xr, int M) {
    __shared__ ushort_t sA[128 * 32];
    __shared__ ushort_t sB[128 * 32];
    int tid = threadIdx.x;
    int wave = tid >> 6, lane = tid & 63;
    int bm = blockIdx.x * 128, bn = blockIdx.y * 128;
    int wr = wave >> 1, wc = wave & 1;
    f32x4 acc[4][4] = {};

    int sr = lane >> 2;          // 0..15: row within a 16-row issue
    int sk = (lane & 3) * 8;     // k element offset (8 bf16 = 16B)
    const ushort_t* gA = A  + (size_t)(bm + sr) * H + sk;
    const ushort_t* gB = Bt + (size_t)(bn + sr) * H + sk;
    int fr = lane & 15, fq = lane >> 4;

    for (int k0 = 0; k0 < H; k0 += 32) {
#pragma unroll
        for (int i = 0; i < 2; ++i) {
            int q = wave * 2 + i;      // wave-uniform issue id 0..7
            __builtin_amdgcn_global_load_lds(
                (const __attribute__((address_space(1))) unsigned*)(gA + (size_t)(16 * q) * H + k0),
                (__attribute__((address_space(3))) unsigned*)(&sA[q * 512]), 16, 0, 0);
            __builtin_amdgcn_global_load_lds(
                (const __attribute__((address_space(1))) unsigned*)(gB + (size_t)(16 * q) * H + k0),
                (__attribute__((address_space(3))) unsigned*)(&sB[q * 512]), 16, 0, 0);
        }
        __syncthreads();
        bf16x8 a[4], b[4];
#pragma unroll
        for (int m = 0; m < 4; ++m)
            a[m] = *(const bf16x8*)&sA[(wr * 64 + m * 16 + fr) * 32 + fq * 8];
#pragma unroll
        for (int n = 0; n < 4; ++n)
            b[n] = *(const bf16x8*)&sB[(wc * 64 + n * 16 + fr) * 32 + fq * 8];
#pragma unroll
        for (int m = 0; m < 4; ++m)
#pragma unroll
            for (int n = 0; n < 4; ++n)
                acc[m][n] = __builtin_amdgcn_mfma_f32_16x16x32_bf16(a[m], b[n], acc[m][n], 0, 0, 0);
        __syncthreads();
    }

    // block-uniform: bn in [0,1536), whole block lands in one half
    const bool left = (bn < H);
    ushort_t* C = left ? xl : xr;
    const float* bias = left ? bl : br;
    int cb = bn - (left ? 0 : H);
#pragma unroll
    for (int n = 0; n < 4; ++n) {
        int col = cb + wc * 64 + n * 16 + fr;
        float bv = bias[col];
#pragma unroll
        for (int m = 0; m < 4; ++m) {
#pragma unroll
            for (int j = 0; j < 4; ++j) {
                int row = bm + wr * 64 + m * 16 + fq * 4 + j;
                if (row < M)
                    C[(size_t)row * H + col] = f2b(acc[m][n][j] + bv);
            }
        }
    }
}

// ------------------------------------------------------------- edge alpha ---
__global__ __launch_bounds__(256) void edge_alpha_kernel(
    const ushort_t* __restrict__ xl, const ushort_t* __restrict__ xr,
    const int* __restrict__ src_s, const int* __restrict__ dst_s,
    const int* __restrict__ eid_s,
    const float* __restrict__ cont, const int* __restrict__ rel,
    const float* __restrict__ We7,   // (7,768) rows 0..6 of We[l]
    const float* __restrict__ WeRel, // (5,768)
    const float* __restrict__ attv,  // (768)
    float* __restrict__ alpha, int E) {
    __shared__ float sWe7[7 * H];
    __shared__ float sRel[5 * H];
    __shared__ float sAtt[H];
    for (int i = threadIdx.x; i < 7 * H; i += 256) sWe7[i] = We7[i];
    for (int i = threadIdx.x; i < 5 * H; i += 256) sRel[i] = WeRel[i];
    for (int i = threadIdx.x; i < H; i += 256) sAtt[i] = attv[i];
    __syncthreads();

    int wave = threadIdx.x >> 6;
    int lane = threadIdx.x & 63;
    int base = blockIdx.x * 128 + wave * 32;
    int end  = base + 32;
    if (end > E) end = E;
    for (int s = base; s < end; ++s) {
        int srcn = src_s[s], dstn = dst_s[s], eid = eid_s[s];
        float c[7];
#pragma unroll
        for (int k = 0; k < 7; ++k) c[k] = cont[(size_t)eid * 7 + k];
        int r = rel[eid];
        const ushort_t* xlp = xl + (size_t)srcn * H;
        const ushort_t* xrp = xr + (size_t)dstn * H;
        float partial = 0.f;
#pragma unroll
        for (int it = 0; it < 6; ++it) {
            int f = lane * 2 + it * 128;
            unsigned ul = *(const unsigned*)(xlp + f);
            unsigned ur = *(const unsigned*)(xrp + f);
#pragma unroll
            for (int half = 0; half < 2; ++half) {
                int fe = f + half;
                float e = sRel[r * H + fe];
#pragma unroll
                for (int k = 0; k < 7; ++k) e = fmaf(c[k], sWe7[k * H + fe], e);
                float xv = b2f((ushort_t)((half ? (ul >> 16) : ul) & 0xffff)) +
                           b2f((ushort_t)((half ? (ur >> 16) : ur) & 0xffff));
                float m = xv + e;
                m = m > 0.f ? m : 0.2f * m;
                partial = fmaf(m, sAtt[fe], partial);
            }
        }
#pragma unroll
        for (int offs = 32; offs; offs >>= 1) partial += __shfl_xor(partial, offs);
        if (lane == 0) alpha[s] = partial;
    }
}

// ---------------------------------------------------------------- softmax ---
__global__ void softmax_kernel(const int* __restrict__ off, float* __restrict__ alpha, int N) {
    int n = blockIdx.x * blockDim.x + threadIdx.x;
    if (n >= N) return;
    int s0 = off[n], s1 = off[n + 1];
    float mx = -1e30f;
    for (int s = s0; s < s1; ++s) mx = fmaxf(mx, alpha[s]);
    float sum = 0.f;
    for (int s = s0; s < s1; ++s) {
        float e = expf(alpha[s] - mx);
        alpha[s] = e;
        sum += e;
    }
    float inv = 1.f / (sum + 1e-16f);
    for (int s = s0; s < s1; ++s) alpha[s] *= inv;
}

// -------------------------------------------------------------- aggregate ---
__global__ __launch_bounds__(256) void aggregate_kernel(
    const ushort_t* __restrict__ xl, const float* __restrict__ alpha,
    const int* __restrict__ src_s, const int* __restrict__ off,
    const float* __restrict__ bias, float* __restrict__ hout,
    ushort_t* __restrict__ hbout, int N) {
    int wave = threadIdx.x >> 6;
    int lane = threadIdx.x & 63;
    int n = blockIdx.x * 4 + wave;
    if (n >= N) return;
    int s0 = off[n], s1 = off[n + 1];
    float acc[3][4] = {};
    for (int s = s0; s < s1; ++s) {
        float a = alpha[s];
        const ushort_t* xlp = xl + (size_t)src_s[s] * H;
#pragma unroll
        for (int seg = 0; seg < 3; ++seg) {
            uint2 u = *(const uint2*)(xlp + lane * 4 + seg * 256);
            acc[seg][0] = fmaf(a, b2f((ushort_t)(u.x & 0xffff)), acc[seg][0]);
            acc[seg][1] = fmaf(a, b2f((ushort_t)(u.x >> 16)),    acc[seg][1]);
            acc[seg][2] = fmaf(a, b2f((ushort_t)(u.y & 0xffff)), acc[seg][2]);
            acc[seg][3] = fmaf(a, b2f((ushort_t)(u.y >> 16)),    acc[seg][3]);
        }
    }
#pragma unroll
    for (int seg = 0; seg < 3; ++seg) {
        int f = lane * 4 + seg * 256;
        float4 v;
        v.x = fmaxf(acc[seg][0] + bias[f + 0], 0.f);
        v.y = fmaxf(acc[seg][1] + bias[f + 1], 0.f);
        v.z = fmaxf(acc[seg][2] + bias[f + 2], 0.f);
        v.w = fmaxf(acc[seg][3] + bias[f + 3], 0.f);
        *(float4*)(hout + (size_t)n * H + f) = v;
        ushort_t b4[4] = { f2b(v.x), f2b(v.y), f2b(v.z), f2b(v.w) };
        *(uint2*)(hbout + (size_t)n * H + f) = *(uint2*)b4;
    }
}

// ------------------------------------------------------------------ launch --
extern "C" void kernel_launch(void* const* d_in, const int* in_sizes, int n_in,
                              void* d_out, int out_size, void* d_ws, size_t ws_size,
                              hipStream_t stream) {
    const float* word_feats = (const float*)d_in[0];
    const float* boxes_norm = (const float*)d_in[1];
    const int*   edge_index = (const int*)d_in[2];
    const float* edge_cont  = (const float*)d_in[3];
    const int*   rel_ids    = (const int*)d_in[4];
    const float* rel_table  = (const float*)d_in[5];
    const float* Wl  = (const float*)d_in[6];
    const float* bl  = (const float*)d_in[7];
    const float* Wr  = (const float*)d_in[8];
    const float* br  = (const float*)d_in[9];
    const float* We  = (const float*)d_in[10];
    const float* att = (const float*)d_in[11];
    const float* bias_out = (const float*)d_in[12];
    float* h = (float*)d_out;

    const int N = in_sizes[0] / H;
    const int E = in_sizes[2] / 2;

    char* wsb = (char*)d_ws;
    size_t off_b = 0;
    auto alloc = [&](size_t bytes) -> void* {
        void* p = wsb + off_b;
        off_b += (bytes + 255) & ~(size_t)255;
        return p;
    };
    ushort_t* hb     = (ushort_t*)alloc((size_t)MPAD * H * 2);
    ushort_t* xl     = (ushort_t*)alloc((size_t)MPAD * H * 2);
    ushort_t* xr     = (ushort_t*)alloc((size_t)MPAD * H * 2);
    ushort_t* WT     = (ushort_t*)alloc((size_t)2 * 2 * H * H * 2); // [L][1536][768]
    int*   counts  = (int*)alloc((size_t)(N + 1) * 4);
    int*   offsets = (int*)alloc((size_t)(N + 1) * 4);
    int*   cursor  = (int*)alloc((size_t)N * 4);
    int*   src_s   = (int*)alloc((size_t)E * 4);
    int*   dst_s   = (int*)alloc((size_t)E * 4);
    int*   eid_s   = (int*)alloc((size_t)E * 4);
    float* alphav  = (float*)alloc((size_t)E * 4);
    float* werel   = (float*)alloc((size_t)2 * 5 * H * 4);

    hipMemsetAsync(counts, 0, (size_t)(N + 1) * 4, stream);
    hipMemsetAsync(hb + (size_t)N * H, 0, (size_t)(MPAD - N) * H * 2, stream);

    count_kernel<<<(E + 255) / 256, 256, 0, stream>>>(edge_index + E, counts, E);
    scan_kernel<<<1, 1024, 0, stream>>>(counts, offsets, cursor, N);
    scatter_kernel<<<(E + 255) / 256, 256, 0, stream>>>(edge_index, cursor, src_s, dst_s, eid_s, E);
    posemb_kernel<<<(int)(((long long)N * H + 255) / 256), 256, 0, stream>>>(
        word_feats, boxes_norm, h, hb, N);
    werel_kernel<<<(2 * 5 * H + 255) / 256, 256, 0, stream>>>(rel_table, We, werel);
    transpose_conv_kernel<<<dim3(H / 32, H / 32, 4), 256, 0, stream>>>(Wl, Wr, WT);

    dim3 ggrid(MPAD / 128, 2 * H / 128);   // 235 x 12
    for (int l = 0; l < 2; ++l) {
        gemm_mfma<<<ggrid, 256, 0, stream>>>(hb, WT + (size_t)l * 2 * H * H,
                                             bl + (size_t)l * H, br + (size_t)l * H,
                                             xl, xr, N);
        edge_alpha_kernel<<<(E + 127) / 128, 256, 0, stream>>>(
            xl, xr, src_s, dst_s, eid_s, edge_cont, rel_ids,
            We + (size_t)l * 23 * H, werel + (size_t)l * 5 * H, att + (size_t)l * H, alphav, E);
        softmax_kernel<<<(N + 255) / 256, 256, 0, stream>>>(offsets, alphav, N);
        aggregate_kernel<<<(N + 3) / 4, 256, 0, stream>>>(xl, alphav, src_s, offsets,
                                                          bias_out + (size_t)l * H, h, hb, N);
    }
}

// Round 5
// 1058.787 us; speedup vs baseline: 1.0291x; 1.0291x over previous
//
#include <hip/hip_runtime.h>
#include <hip/hip_bf16.h>

#define H 768
#define MPAD 30080   // 235 * 128

typedef unsigned short ushort_t;
typedef __attribute__((ext_vector_type(8))) short bf16x8;
typedef __attribute__((ext_vector_type(4))) float f32x4;
typedef __attribute__((ext_vector_type(2))) float f32x2;

__device__ __forceinline__ float b2f(ushort_t u) {
    unsigned x = ((unsigned)u) << 16;
    float f; __builtin_memcpy(&f, &x, 4); return f;
}
__device__ __forceinline__ ushort_t f2b(float f) {
    unsigned x; __builtin_memcpy(&x, &f, 4);
    unsigned r = (x + 0x7FFFu + ((x >> 16) & 1u)) >> 16;
    return (ushort_t)r;
}

// ---------------------------------------------------------------- pos emb ---
// writes only hb (bf16); f32 h is produced by the final layer's gat kernel
__global__ void posemb_kernel(const float* __restrict__ wf,
                              const float* __restrict__ bn,
                              ushort_t* __restrict__ hb, int N) {
    long long idx = (long long)blockIdx.x * blockDim.x + threadIdx.x;
    if (idx >= (long long)N * H) return;
    int n = (int)(idx / H);
    int f = (int)(idx % H);
    int c = f / 192;
    int j = f % 192;
    int k = (j < 96) ? j : j - 96;
    float invf = __expf(-((float)(2 * k) / 192.0f) * 9.210340371976184f);
    float v = bn[n * 4 + c] * invf;
    float pe = (j < 96) ? __sinf(v) : __cosf(v);
    hb[idx] = f2b(wf[idx] + pe);
}

// ---------------------------------------------------------------- CSR build --
__global__ void count_kernel(const int* __restrict__ dst, int* __restrict__ counts, int E) {
    int e = blockIdx.x * blockDim.x + threadIdx.x;
    if (e >= E) return;
    atomicAdd(&counts[dst[e]], 1);
}

__global__ void scan_kernel(const int* __restrict__ counts,
                            int* __restrict__ offsets,
                            int* __restrict__ cursor, int n) {
    __shared__ int partial[1024];
    int tid = threadIdx.x;
    int per = (n + 1023) / 1024;
    int base = tid * per;
    int sum = 0;
    for (int i = 0; i < per; ++i) {
        int idx = base + i;
        if (idx < n) sum += counts[idx];
    }
    partial[tid] = sum;
    __syncthreads();
    for (int offs = 1; offs < 1024; offs <<= 1) {
        int v = 0;
        if (tid >= offs) v = partial[tid - offs];
        __syncthreads();
        if (tid >= offs) partial[tid] += v;
        __syncthreads();
    }
    int running = (tid == 0) ? 0 : partial[tid - 1];
    for (int i = 0; i < per; ++i) {
        int idx = base + i;
        if (idx < n) {
            offsets[idx] = running;
            cursor[idx]  = running;
            running += counts[idx];
        }
    }
    if (tid == 0) offsets[n] = partial[1023];
}

__global__ void scatter_kernel(const int* __restrict__ ei, int* __restrict__ cursor,
                               int* __restrict__ src_s, int* __restrict__ eid_s, int E) {
    int e = blockIdx.x * blockDim.x + threadIdx.x;
    if (e >= E) return;
    int s = ei[e], d = ei[E + e];
    int p = atomicAdd(&cursor[d], 1);
    src_s[p] = s;
    eid_s[p] = e;
}

// ------------------------------------------------------- We_rel precompute ---
__global__ void werel_kernel(const float* __restrict__ rel_table,
                             const float* __restrict__ We,
                             float* __restrict__ werel) {
    int idx = blockIdx.x * blockDim.x + threadIdx.x;
    if (idx >= 2 * 5 * H) return;
    int f = idx % H;
    int r = (idx / H) % 5;
    int l = idx / (5 * H);
    const float* Wep = We + (size_t)l * 23 * H;
    float s = 0.f;
#pragma unroll
    for (int k = 0; k < 16; ++k)
        s = fmaf(rel_table[r * 16 + k], Wep[(size_t)(7 + k) * H + f], s);
    werel[idx] = s;
}

// -------------------------------------------- weight transpose + bf16 cast ---
// WT[l] layout: [1536][768] bf16; rows 0..767 = Wl[l]^T, rows 768..1535 = Wr[l]^T
__global__ __launch_bounds__(256) void transpose_conv_kernel(
    const float* __restrict__ Wl, const float* __restrict__ Wr,
    ushort_t* __restrict__ WT) {
    __shared__ float t[32][33];
    int z = blockIdx.z;                 // 0:Wl0 1:Wl1 2:Wr0 3:Wr1
    const float* src = ((z < 2) ? Wl : Wr) + (size_t)(z & 1) * H * H;
    ushort_t*    dst = WT + (size_t)(z & 1) * 2 * H * H + ((z < 2) ? 0 : (size_t)H * H);
    int k0 = blockIdx.x * 32, n0 = blockIdx.y * 32;
    int tx = threadIdx.x & 31, ty = threadIdx.x >> 5;   // 32 x 8
#pragma unroll
    for (int r = 0; r < 4; ++r)
        t[ty + 8 * r][tx] = src[(size_t)(k0 + ty + 8 * r) * H + n0 + tx];
    __syncthreads();
#pragma unroll
    for (int r = 0; r < 4; ++r)
        dst[(size_t)(n0 + ty + 8 * r) * H + k0 + tx] = f2b(t[tx][ty + 8 * r]);
}

// ------------------------------------------------------------ MFMA GEMM -----
// [xl | xr][M][768] = A[MPAD][768](bf16) @ WT[1536][768]^T + [bl | br]
// grid (x=bn:12, y=bm:235): consecutive blocks reuse the same A panel in L2.
// Epilogue staged through LDS for coalesced 16B stores.
__global__ __launch_bounds__(256) void gemm_mfma(
    const ushort_t* __restrict__ A,
    const ushort_t* __restrict__ Bt,   // [1536][768]
    const float* __restrict__ bl, const float* __restrict__ br,
    ushort_t* __restrict__ xl, ushort_t* __restrict__ xr, int M) {
    __shared__ __align__(16) ushort_t smem[8192];   // 16 KB: sA 8KB | sB 8KB
    ushort_t* sA = smem;
    ushort_t* sB = smem + 4096;
    int tid = threadIdx.x;
    int wave = tid >> 6, lane = tid & 63;
    int bn = blockIdx.x * 128, bm = blockIdx.y * 128;
    int wr = wave >> 1, wc = wave & 1;
    f32x4 acc[4][4] = {};

    int sr = lane >> 2;          // 0..15: row within a 16-row issue
    int sk = (lane & 3) * 8;     // k element offset (8 bf16 = 16B)
    const ushort_t* gA = A  + (size_t)(bm + sr) * H + sk;
    const ushort_t* gB = Bt + (size_t)(bn + sr) * H + sk;
    int fr = lane & 15, fq = lane >> 4;

    for (int k0 = 0; k0 < H; k0 += 32) {
#pragma unroll
        for (int i = 0; i < 2; ++i) {
            int q = wave * 2 + i;      // wave-uniform issue id 0..7
            __builtin_amdgcn_global_load_lds(
                (const __attribute__((address_space(1))) unsigned*)(gA + (size_t)(16 * q) * H + k0),
                (__attribute__((address_space(3))) unsigned*)(sA + q * 512), 16, 0, 0);
            __builtin_amdgcn_global_load_lds(
                (const __attribute__((address_space(1))) unsigned*)(gB + (size_t)(16 * q) * H + k0),
                (__attribute__((address_space(3))) unsigned*)(sB + q * 512), 16, 0, 0);
        }
        __syncthreads();
        bf16x8 a[4], b[4];
#pragma unroll
        for (int m = 0; m < 4; ++m)
            a[m] = *(const bf16x8*)&sA[(wr * 64 + m * 16 + fr) * 32 + fq * 8];
#pragma unroll
        for (int n = 0; n < 4; ++n)
            b[n] = *(const bf16x8*)&sB[(wc * 64 + n * 16 + fr) * 32 + fq * 8];
#pragma unroll
        for (int m = 0; m < 4; ++m)
#pragma unroll
            for (int n = 0; n < 4; ++n)
                acc[m][n] = __builtin_amdgcn_mfma_f32_16x16x32_bf16(a[m], b[n], acc[m][n], 0, 0, 0);
        __syncthreads();
    }

    // block-uniform destination select
    const bool left = (bn < H);
    ushort_t* Cp = left ? xl : xr;
    const float* bias = left ? bl : br;
    int cb = bn - (left ? 0 : H);
    float bv[4];
#pragma unroll
    for (int n = 0; n < 4; ++n) bv[n] = bias[cb + wc * 64 + n * 16 + fr];

    // epilogue: stage 64x128 bf16 (16 KB) halves through LDS, coalesced stores
    ushort_t* sC = smem;   // 8192 entries = 16 KB
#pragma unroll
    for (int hh = 0; hh < 2; ++hh) {
        if (wr == hh) {
#pragma unroll
            for (int m = 0; m < 4; ++m)
#pragma unroll
                for (int n = 0; n < 4; ++n) {
                    int col = wc * 64 + n * 16 + fr;
#pragma unroll
                    for (int j = 0; j < 4; ++j) {
                        int rloc = m * 16 + fq * 4 + j;     // 0..63
                        sC[rloc * 128 + col] = f2b(acc[m][n][j] + bv[n]);
                    }
                }
        }
        __syncthreads();
        int rowg0 = bm + hh * 64;
#pragma unroll
        for (int i = 0; i < 4; ++i) {
            int t16 = i * 256 + tid;        // 1024 chunks of 16B
            int rloc = t16 >> 4;            // 16 chunks per 128-col row
            int cchunk = t16 & 15;
            int rowg = rowg0 + rloc;
            if (rowg < M)
                *(uint4*)(Cp + (size_t)rowg * H + cb + cchunk * 8) =
                    *(const uint4*)&sC[rloc * 128 + cchunk * 8];
        }
        __syncthreads();
    }
}

// ---------------------------------------- fused GATv2 per-node edge phase ---
// One wave per dst node: xr row in registers; per incoming edge gather xl[src]
// once, compute alpha, online-softmax accumulate. Then bias+relu+write.
__global__ __launch_bounds__(256) void gat_node_kernel(
    const ushort_t* __restrict__ xl, const ushort_t* __restrict__ xr,
    const int* __restrict__ src_s, const int* __restrict__ eid_s,
    const int* __restrict__ off,
    const float* __restrict__ cont, const int* __restrict__ rel,
    const float* __restrict__ We7,   // (7,768)
    const float* __restrict__ WeRel, // (5,768)
    const float* __restrict__ attv,  // (768)
    const float* __restrict__ bias,
    float* __restrict__ hout, ushort_t* __restrict__ hbout,
    int N, int writeF32) {
    __shared__ float sWe7[7 * H];
    __shared__ float sRel[5 * H];
    __shared__ float sAtt[H];
    for (int i = threadIdx.x; i < 7 * H; i += 256) sWe7[i] = We7[i];
    for (int i = threadIdx.x; i < 5 * H; i += 256) sRel[i] = WeRel[i];
    for (int i = threadIdx.x; i < H; i += 256) sAtt[i] = attv[i];
    __syncthreads();

    int wave = threadIdx.x >> 6;
    int lane = threadIdx.x & 63;
    int n = blockIdx.x * 4 + wave;
    if (n >= N) return;
    int s0 = off[n], s1 = off[n + 1];

    // xr row: 12 features per lane at f = lane*2 + it*128 (+0/+1)
    f32x2 xrv[6];
    {
        const ushort_t* xrp = xr + (size_t)n * H;
#pragma unroll
        for (int it = 0; it < 6; ++it) {
            unsigned u = *(const unsigned*)(xrp + lane * 2 + it * 128);
            xrv[it].x = b2f((ushort_t)(u & 0xffff));
            xrv[it].y = b2f((ushort_t)(u >> 16));
        }
    }

    float m_run = -1e30f, s_run = 0.f;
    f32x2 acc[6] = {};

    for (int s = s0; s < s1; ++s) {
        int srcn = src_s[s], eid = eid_s[s];
        float c[7];
#pragma unroll
        for (int k = 0; k < 7; ++k) c[k] = cont[(size_t)eid * 7 + k];
        int r = rel[eid];
        const ushort_t* xlp = xl + (size_t)srcn * H;

        f32x2 xv[6];
#pragma unroll
        for (int it = 0; it < 6; ++it) {
            unsigned u = *(const unsigned*)(xlp + lane * 2 + it * 128);
            xv[it].x = b2f((ushort_t)(u & 0xffff));
            xv[it].y = b2f((ushort_t)(u >> 16));
        }

        f32x2 part2 = {0.f, 0.f};
#pragma unroll
        for (int it = 0; it < 6; ++it) {
            int f = lane * 2 + it * 128;
            f32x2 e2 = *(const f32x2*)&sRel[r * H + f];
#pragma unroll
            for (int k = 0; k < 7; ++k)
                e2 = (*(const f32x2*)&sWe7[k * H + f]) * c[k] + e2;
            f32x2 mm = xv[it] + xrv[it] + e2;
            f32x2 lk;
            lk.x = fmaxf(mm.x, 0.f) + 0.2f * fminf(mm.x, 0.f);
            lk.y = fmaxf(mm.y, 0.f) + 0.2f * fminf(mm.y, 0.f);
            part2 = lk * (*(const f32x2*)&sAtt[f]) + part2;
        }
        float p = part2.x + part2.y;
#pragma unroll
        for (int o = 32; o; o >>= 1) p += __shfl_xor(p, o);
        // p == alpha for this edge, uniform across the wave
        if (p > m_run) {
            float scale = __expf(m_run - p);
            s_run *= scale;
#pragma unroll
            for (int it = 0; it < 6; ++it) acc[it] = acc[it] * scale;
            m_run = p;
        }
        float w = __expf(p - m_run);
        s_run += w;
#pragma unroll
        for (int it = 0; it < 6; ++it) acc[it] = xv[it] * w + acc[it];
    }

    float inv = (s_run > 0.f) ? 1.f / (s_run + 1e-16f) : 0.f;
#pragma unroll
    for (int it = 0; it < 6; ++it) {
        int f = lane * 2 + it * 128;
        f32x2 b2 = *(const f32x2*)&bias[f];
        float v0 = fmaxf(acc[it].x * inv + b2.x, 0.f);
        float v1 = fmaxf(acc[it].y * inv + b2.y, 0.f);
        if (writeF32) {
            float2 o; o.x = v0; o.y = v1;
            *(float2*)(hout + (size_t)n * H + f) = o;
        }
        unsigned pk = (unsigned)f2b(v0) | ((unsigned)f2b(v1) << 16);
        *(unsigned*)(hbout + (size_t)n * H + f) = pk;
    }
}

// ------------------------------------------------------------------ launch --
extern "C" void kernel_launch(void* const* d_in, const int* in_sizes, int n_in,
                              void* d_out, int out_size, void* d_ws, size_t ws_size,
                              hipStream_t stream) {
    const float* word_feats = (const float*)d_in[0];
    const float* boxes_norm = (const float*)d_in[1];
    const int*   edge_index = (const int*)d_in[2];
    const float* edge_cont  = (const float*)d_in[3];
    const int*   rel_ids    = (const int*)d_in[4];
    const float* rel_table  = (const float*)d_in[5];
    const float* Wl  = (const float*)d_in[6];
    const float* bl  = (const float*)d_in[7];
    const float* Wr  = (const float*)d_in[8];
    const float* br  = (const float*)d_in[9];
    const float* We  = (const float*)d_in[10];
    const float* att = (const float*)d_in[11];
    const float* bias_out = (const float*)d_in[12];
    float* h = (float*)d_out;

    const int N = in_sizes[0] / H;
    const int E = in_sizes[2] / 2;

    char* wsb = (char*)d_ws;
    size_t off_b = 0;
    auto alloc = [&](size_t bytes) -> void* {
        void* p = wsb + off_b;
        off_b += (bytes + 255) & ~(size_t)255;
        return p;
    };
    ushort_t* hb     = (ushort_t*)alloc((size_t)MPAD * H * 2);
    ushort_t* xl     = (ushort_t*)alloc((size_t)MPAD * H * 2);
    ushort_t* xr     = (ushort_t*)alloc((size_t)MPAD * H * 2);
    ushort_t* WT     = (ushort_t*)alloc((size_t)2 * 2 * H * H * 2); // [L][1536][768]
    int*   counts  = (int*)alloc((size_t)(N + 1) * 4);
    int*   offsets = (int*)alloc((size_t)(N + 1) * 4);
    int*   cursor  = (int*)alloc((size_t)N * 4);
    int*   src_s   = (int*)alloc((size_t)E * 4);
    int*   eid_s   = (int*)alloc((size_t)E * 4);
    float* werel   = (float*)alloc((size_t)2 * 5 * H * 4);

    hipMemsetAsync(counts, 0, (size_t)(N + 1) * 4, stream);
    hipMemsetAsync(hb + (size_t)N * H, 0, (size_t)(MPAD - N) * H * 2, stream);

    count_kernel<<<(E + 255) / 256, 256, 0, stream>>>(edge_index + E, counts, E);
    scan_kernel<<<1, 1024, 0, stream>>>(counts, offsets, cursor, N);
    scatter_kernel<<<(E + 255) / 256, 256, 0, stream>>>(edge_index, cursor, src_s, eid_s, E);
    posemb_kernel<<<(int)(((long long)N * H + 255) / 256), 256, 0, stream>>>(
        word_feats, boxes_norm, hb, N);
    werel_kernel<<<(2 * 5 * H + 255) / 256, 256, 0, stream>>>(rel_table, We, werel);
    transpose_conv_kernel<<<dim3(H / 32, H / 32, 4), 256, 0, stream>>>(Wl, Wr, WT);

    dim3 ggrid(2 * H / 128, MPAD / 128);   // x=bn (12), y=bm (235)
    for (int l = 0; l < 2; ++l) {
        gemm_mfma<<<ggrid, 256, 0, stream>>>(hb, WT + (size_t)l * 2 * H * H,
                                             bl + (size_t)l * H, br + (size_t)l * H,
                                             xl, xr, N);
        gat_node_kernel<<<(N + 3) / 4, 256, 0, stream>>>(
            xl, xr, src_s, eid_s, offsets, edge_cont, rel_ids,
            We + (size_t)l * 23 * H, werel + (size_t)l * 5 * H, att + (size_t)l * H,
            bias_out + (size_t)l * H, h, hb, N, l == 1);
    }
}

// Round 11
// 858.381 us; speedup vs baseline: 1.2694x; 1.2335x over previous
//
#include <hip/hip_runtime.h>
#include <hip/hip_bf16.h>

#define H 768
#define MPAD 30080   // 235 * 128
#define CELLG 32     // spatial sort grid (32x32 = 1024 cells)

typedef unsigned short ushort_t;
typedef __attribute__((ext_vector_type(8))) short bf16x8;
typedef __attribute__((ext_vector_type(4))) float f32x4;
typedef __attribute__((ext_vector_type(2))) float f32x2;

__device__ __forceinline__ float b2f(ushort_t u) {
    unsigned x = ((unsigned)u) << 16;
    float f; __builtin_memcpy(&f, &x, 4); return f;
}
__device__ __forceinline__ ushort_t f2b(float f) {
    unsigned x; __builtin_memcpy(&x, &f, 4);
    unsigned r = (x + 0x7FFFu + ((x >> 16) & 1u)) >> 16;
    return (ushort_t)r;
}
// unpack 2 packed bf16 (lo,hi) -> f32x2, 2 bit-ops
__device__ __forceinline__ f32x2 up2(unsigned u) {
    unsigned lo = u << 16, hi = u & 0xffff0000u;
    float flo, fhi;
    __builtin_memcpy(&flo, &lo, 4);
    __builtin_memcpy(&fhi, &hi, 4);
    f32x2 r;
    r.x = flo;
    r.y = fhi;
    return r;
}

// ---------------------------------------------------------------- pos emb ---
__global__ void posemb_kernel(const float* __restrict__ wf,
                              const float* __restrict__ bn,
                              ushort_t* __restrict__ hb, int N) {
    long long idx = (long long)blockIdx.x * blockDim.x + threadIdx.x;
    if (idx >= (long long)N * H) return;
    int n = (int)(idx / H);
    int f = (int)(idx % H);
    int c = f / 192;
    int j = f % 192;
    int k = (j < 96) ? j : j - 96;
    float invf = __expf(-((float)(2 * k) / 192.0f) * 9.210340371976184f);
    float v = bn[n * 4 + c] * invf;
    float pe = (j < 96) ? __sinf(v) : __cosf(v);
    hb[idx] = f2b(wf[idx] + pe);
}

// ---------------------------------------------------------------- CSR build --
__global__ void count_kernel(const int* __restrict__ dst, int* __restrict__ counts, int E) {
    int e = blockIdx.x * blockDim.x + threadIdx.x;
    if (e >= E) return;
    atomicAdd(&counts[dst[e]], 1);
}

__global__ void scan_kernel(const int* __restrict__ counts,
                            int* __restrict__ offsets,
                            int* __restrict__ cursor, int n) {
    __shared__ int partial[1024];
    int tid = threadIdx.x;
    int per = (n + 1023) / 1024;
    int base = tid * per;
    int sum = 0;
    for (int i = 0; i < per; ++i) {
        int idx = base + i;
        if (idx < n) sum += counts[idx];
    }
    partial[tid] = sum;
    __syncthreads();
    for (int offs = 1; offs < 1024; offs <<= 1) {
        int v = 0;
        if (tid >= offs) v = partial[tid - offs];
        __syncthreads();
        if (tid >= offs) partial[tid] += v;
        __syncthreads();
    }
    int running = (tid == 0) ? 0 : partial[tid - 1];
    for (int i = 0; i < per; ++i) {
        int idx = base + i;
        if (idx < n) {
            offsets[idx] = running;
            cursor[idx]  = running;
            running += counts[idx];
        }
    }
    if (tid == 0) offsets[n] = partial[1023];
}

// scatter + pack per-edge payload {cont[0..6], (float)rel} into dst-sorted order
__global__ void scatter_kernel(const int* __restrict__ ei,
                               const float* __restrict__ cont,
                               const int* __restrict__ rel,
                               int* __restrict__ cursor,
                               int* __restrict__ src_s,
                               float* __restrict__ cpk, int E) {
    int e = blockIdx.x * blockDim.x + threadIdx.x;
    if (e >= E) return;
    int s = ei[e], d = ei[E + e];
    int p = atomicAdd(&cursor[d], 1);
    src_s[p] = s;
    float c[8];
#pragma unroll
    for (int k = 0; k < 7; ++k) c[k] = cont[(size_t)e * 7 + k];
    c[7] = (float)rel[e];
    *(float4*)(cpk + (size_t)p * 8)     = make_float4(c[0], c[1], c[2], c[3]);
    *(float4*)(cpk + (size_t)p * 8 + 4) = make_float4(c[4], c[5], c[6], c[7]);
}

// ------------------------------------------------------ spatial node order ---
__device__ __forceinline__ int cell_of(const float* bn, int n) {
    float cx = (bn[n * 4 + 0] + bn[n * 4 + 2]) * 0.5f;   // [0,1]
    float cy = (bn[n * 4 + 1] + bn[n * 4 + 3]) * 0.5f;
    int ix = (int)(cx * CELLG); ix = ix < 0 ? 0 : (ix > CELLG - 1 ? CELLG - 1 : ix);
    int iy = (int)(cy * CELLG); iy = iy < 0 ? 0 : (iy > CELLG - 1 ? CELLG - 1 : iy);
    return iy * CELLG + ix;
}

__global__ void cell_count_kernel(const float* __restrict__ bn, int* __restrict__ cellcnt, int N) {
    int n = blockIdx.x * blockDim.x + threadIdx.x;
    if (n >= N) return;
    atomicAdd(&cellcnt[cell_of(bn, n)], 1);
}

__global__ void cell_scatter_kernel(const float* __restrict__ bn, int* __restrict__ cellcur,
                                    int* __restrict__ order, int N) {
    int n = blockIdx.x * blockDim.x + threadIdx.x;
    if (n >= N) return;
    int p = atomicAdd(&cellcur[cell_of(bn, n)], 1);
    order[p] = n;
}

// --------------------------------------------- bf16 fused table (13 x 768) ---
// rows 0..6 = We[l][0..6]; rows 7..11 = rel_table[r] @ We[l][7..22]; row 12 = att[l]
__global__ void tab_build_kernel(const float* __restrict__ We,
                                 const float* __restrict__ rel_table,
                                 const float* __restrict__ att,
                                 ushort_t* __restrict__ tabG) {
    int idx = blockIdx.x * blockDim.x + threadIdx.x;
    if (idx >= 2 * 13 * H) return;
    int f = idx % H;
    int row = (idx / H) % 13;
    int l = idx / (13 * H);
    const float* Wep = We + (size_t)l * 23 * H;
    float v;
    if (row < 7) {
        v = Wep[(size_t)row * H + f];
    } else if (row < 12) {
        int r = row - 7;
        v = 0.f;
#pragma unroll
        for (int k = 0; k < 16; ++k)
            v = fmaf(rel_table[r * 16 + k], Wep[(size_t)(7 + k) * H + f], v);
    } else {
        v = att[(size_t)l * H + f];
    }
    tabG[idx] = f2b(v);
}

// -------------------------------------------- weight transpose + bf16 cast ---
__global__ __launch_bounds__(256) void transpose_conv_kernel(
    const float* __restrict__ Wl, const float* __restrict__ Wr,
    ushort_t* __restrict__ WT) {
    __shared__ float t[32][33];
    int z = blockIdx.z;                 // 0:Wl0 1:Wl1 2:Wr0 3:Wr1
    const float* src = ((z < 2) ? Wl : Wr) + (size_t)(z & 1) * H * H;
    ushort_t*    dst = WT + (size_t)(z & 1) * 2 * H * H + ((z < 2) ? 0 : (size_t)H * H);
    int k0 = blockIdx.x * 32, n0 = blockIdx.y * 32;
    int tx = threadIdx.x & 31, ty = threadIdx.x >> 5;   // 32 x 8
#pragma unroll
    for (int r = 0; r < 4; ++r)
        t[ty + 8 * r][tx] = src[(size_t)(k0 + ty + 8 * r) * H + n0 + tx];
    __syncthreads();
#pragma unroll
    for (int r = 0; r < 4; ++r)
        dst[(size_t)(n0 + ty + 8 * r) * H + k0 + tx] = f2b(t[tx][ty + 8 * r]);
}

// ------------------------------------------------------------ MFMA GEMM -----
__global__ __launch_bounds__(256) void gemm_mfma(
    const ushort_t* __restrict__ A,
    const ushort_t* __restrict__ Bt,   // [1536][768]
    const float* __restrict__ bl, const float* __restrict__ br,
    ushort_t* __restrict__ xl, ushort_t* __restrict__ xr, int M) {
    __shared__ __align__(16) ushort_t smem[8192];   // 16 KB: sA 8KB | sB 8KB
    ushort_t* sA = smem;
    ushort_t* sB = smem + 4096;
    int tid = threadIdx.x;
    int wave = tid >> 6, lane = tid & 63;
    int bn = blockIdx.x * 128, bm = blockIdx.y * 128;
    int wr = wave >> 1, wc = wave & 1;
    f32x4 acc[4][4] = {};

    int sr = lane >> 2;
    int sk = (lane & 3) * 8;
    const ushort_t* gA = A  + (size_t)(bm + sr) * H + sk;
    const ushort_t* gB = Bt + (size_t)(bn + sr) * H + sk;
    int fr = lane & 15, fq = lane >> 4;

    for (int k0 = 0; k0 < H; k0 += 32) {
#pragma unroll
        for (int i = 0; i < 2; ++i) {
            int q = wave * 2 + i;
            __builtin_amdgcn_global_load_lds(
                (const __attribute__((address_space(1))) unsigned*)(gA + (size_t)(16 * q) * H + k0),
                (__attribute__((address_space(3))) unsigned*)(sA + q * 512), 16, 0, 0);
            __builtin_amdgcn_global_load_lds(
                (const __attribute__((address_space(1))) unsigned*)(gB + (size_t)(16 * q) * H + k0),
                (__attribute__((address_space(3))) unsigned*)(sB + q * 512), 16, 0, 0);
        }
        __syncthreads();
        bf16x8 a[4], b[4];
#pragma unroll
        for (int m = 0; m < 4; ++m)
            a[m] = *(const bf16x8*)&sA[(wr * 64 + m * 16 + fr) * 32 + fq * 8];
#pragma unroll
        for (int n = 0; n < 4; ++n)
            b[n] = *(const bf16x8*)&sB[(wc * 64 + n * 16 + fr) * 32 + fq * 8];
#pragma unroll
        for (int m = 0; m < 4; ++m)
#pragma unroll
            for (int n = 0; n < 4; ++n)
                acc[m][n] = __builtin_amdgcn_mfma_f32_16x16x32_bf16(a[m], b[n], acc[m][n], 0, 0, 0);
        __syncthreads();
    }

    const bool left = (bn < H);
    ushort_t* Cp = left ? xl : xr;
    const float* bias = left ? bl : br;
    int cb = bn - (left ? 0 : H);
    float bv[4];
#pragma unroll
    for (int n = 0; n < 4; ++n) bv[n] = bias[cb + wc * 64 + n * 16 + fr];

    ushort_t* sC = smem;
#pragma unroll
    for (int hh = 0; hh < 2; ++hh) {
        if (wr == hh) {
#pragma unroll
            for (int m = 0; m < 4; ++m)
#pragma unroll
                for (int n = 0; n < 4; ++n) {
                    int col = wc * 64 + n * 16 + fr;
#pragma unroll
                    for (int j = 0; j < 4; ++j) {
                        int rloc = m * 16 + fq * 4 + j;
                        sC[rloc * 128 + col] = f2b(acc[m][n][j] + bv[n]);
                    }
                }
        }
        __syncthreads();
        int rowg0 = bm + hh * 64;
#pragma unroll
        for (int i = 0; i < 4; ++i) {
            int t16 = i * 256 + tid;
            int rloc = t16 >> 4;
            int cchunk = t16 & 15;
            int rowg = rowg0 + rloc;
            if (rowg < M)
                *(uint4*)(Cp + (size_t)rowg * H + cb + cchunk * 8) =
                    *(const uint4*)&sC[rloc * 128 + cchunk * 8];
        }
        __syncthreads();
    }
}

// ---------------------------------------- fused GATv2 per-node edge phase ---
// wave g processes order[NPW*g .. NPW*g+NPW-1]; bf16 tables in LDS;
// 2-edge pipelined branchless online softmax.
#define NPW 4
__global__ __launch_bounds__(256) void gat_node_kernel(
    const ushort_t* __restrict__ xl, const ushort_t* __restrict__ xr,
    const int* __restrict__ src_s, const float* __restrict__ cpk,
    const int* __restrict__ off, const int* __restrict__ order,
    const ushort_t* __restrict__ tabG,   // 13*768 bf16 for this layer
    const float* __restrict__ bias,
    float* __restrict__ hout, ushort_t* __restrict__ hbout,
    int N, int writeF32) {
    __shared__ ushort_t sTab[13 * H];
    for (int i = threadIdx.x; i < 13 * H / 2; i += 256)
        ((unsigned*)sTab)[i] = ((const unsigned*)tabG)[i];
    __syncthreads();

    int wave = threadIdx.x >> 6;
    int lane = threadIdx.x & 63;
    int gw = blockIdx.x * 4 + wave;

    for (int j = 0; j < NPW; ++j) {
        int oi = gw * NPW + j;
        if (oi >= N) return;
        int n = order[oi];
        int s0 = off[n], s1 = off[n + 1];

        f32x2 xrv[6];
        {
            const ushort_t* xrp = xr + (size_t)n * H;
#pragma unroll
            for (int it = 0; it < 6; ++it)
                xrv[it] = up2(*(const unsigned*)(xrp + lane * 2 + it * 128));
        }

        float m_run = -1e30f, s_run = 0.f;
        f32x2 acc[6] = {};
        int s = s0;

        for (; s + 2 <= s1; s += 2) {
            int srcA = src_s[s], srcB = src_s[s + 1];
            float4 ca0 = *(const float4*)(cpk + (size_t)s * 8);
            float4 ca1 = *(const float4*)(cpk + (size_t)s * 8 + 4);
            float4 cb0 = *(const float4*)(cpk + (size_t)(s + 1) * 8);
            float4 cb1 = *(const float4*)(cpk + (size_t)(s + 1) * 8 + 4);
            int rA = (int)ca1.w, rB = (int)cb1.w;
            const ushort_t* pa = xl + (size_t)srcA * H;
            const ushort_t* pb = xl + (size_t)srcB * H;
            float cA[7] = {ca0.x, ca0.y, ca0.z, ca0.w, ca1.x, ca1.y, ca1.z};
            float cB[7] = {cb0.x, cb0.y, cb0.z, cb0.w, cb1.x, cb1.y, cb1.z};

            f32x2 xa[6], xb[6];
#pragma unroll
            for (int it = 0; it < 6; ++it) {
                xa[it] = up2(*(const unsigned*)(pa + lane * 2 + it * 128));
                xb[it] = up2(*(const unsigned*)(pb + lane * 2 + it * 128));
            }

            f32x2 sa = {0.f, 0.f}, sb = {0.f, 0.f};
#pragma unroll
            for (int it = 0; it < 6; ++it) {
                int f = lane * 2 + it * 128;
                f32x2 e_a = up2(*(const unsigned*)(sTab + (7 + rA) * H + f));
                f32x2 e_b = up2(*(const unsigned*)(sTab + (7 + rB) * H + f));
#pragma unroll
                for (int k = 0; k < 7; ++k) {
                    f32x2 w = up2(*(const unsigned*)(sTab + k * H + f));
                    e_a = w * cA[k] + e_a;
                    e_b = w * cB[k] + e_b;
                }
                f32x2 mA = xa[it] + xrv[it] + e_a;
                f32x2 mB = xb[it] + xrv[it] + e_b;
                f32x2 lA, lB;
                lA.x = fmaxf(mA.x, 0.f) + 0.2f * fminf(mA.x, 0.f);
                lA.y = fmaxf(mA.y, 0.f) + 0.2f * fminf(mA.y, 0.f);
                lB.x = fmaxf(mB.x, 0.f) + 0.2f * fminf(mB.x, 0.f);
                lB.y = fmaxf(mB.y, 0.f) + 0.2f * fminf(mB.y, 0.f);
                f32x2 av = up2(*(const unsigned*)(sTab + 12 * H + f));
                sa = lA * av + sa;
                sb = lB * av + sb;
            }
            float pA = sa.x + sa.y, pB = sb.x + sb.y;
#pragma unroll
            for (int o = 32; o; o >>= 1) {
                pA += __shfl_xor(pA, o);
                pB += __shfl_xor(pB, o);
            }
            float mnew = fmaxf(m_run, fmaxf(pA, pB));
            float scale = __expf(m_run - mnew);
            float wA = __expf(pA - mnew);
            float wB = __expf(pB - mnew);
            s_run = s_run * scale + wA + wB;
#pragma unroll
            for (int it = 0; it < 6; ++it)
                acc[it] = acc[it] * scale + xa[it] * wA + xb[it] * wB;
            m_run = mnew;
        }

        if (s < s1) {   // tail edge
            int srcA = src_s[s];
            float4 ca0 = *(const float4*)(cpk + (size_t)s * 8);
            float4 ca1 = *(const float4*)(cpk + (size_t)s * 8 + 4);
            int rA = (int)ca1.w;
            const ushort_t* pa = xl + (size_t)srcA * H;
            float cA[7] = {ca0.x, ca0.y, ca0.z, ca0.w, ca1.x, ca1.y, ca1.z};
            f32x2 xa[6];
#pragma unroll
            for (int it = 0; it < 6; ++it)
                xa[it] = up2(*(const unsigned*)(pa + lane * 2 + it * 128));
            f32x2 sa = {0.f, 0.f};
#pragma unroll
            for (int it = 0; it < 6; ++it) {
                int f = lane * 2 + it * 128;
                f32x2 e_a = up2(*(const unsigned*)(sTab + (7 + rA) * H + f));
#pragma unroll
                for (int k = 0; k < 7; ++k) {
                    f32x2 w = up2(*(const unsigned*)(sTab + k * H + f));
                    e_a = w * cA[k] + e_a;
                }
                f32x2 mA = xa[it] + xrv[it] + e_a;
                f32x2 lA;
                lA.x = fmaxf(mA.x, 0.f) + 0.2f * fminf(mA.x, 0.f);
                lA.y = fmaxf(mA.y, 0.f) + 0.2f * fminf(mA.y, 0.f);
                f32x2 av = up2(*(const unsigned*)(sTab + 12 * H + f));
                sa = lA * av + sa;
            }
            float pA = sa.x + sa.y;
#pragma unroll
            for (int o = 32; o; o >>= 1) pA += __shfl_xor(pA, o);
            float mnew = fmaxf(m_run, pA);
            float scale = __expf(m_run - mnew);
            float wA = __expf(pA - mnew);
            s_run = s_run * scale + wA;
#pragma unroll
            for (int it = 0; it < 6; ++it)
                acc[it] = acc[it] * scale + xa[it] * wA;
            m_run = mnew;
        }

        float inv = (s_run > 0.f) ? 1.f / (s_run + 1e-16f) : 0.f;
#pragma unroll
        for (int it = 0; it < 6; ++it) {
            int f = lane * 2 + it * 128;
            f32x2 b2 = *(const f32x2*)&bias[f];
            float v0 = fmaxf(acc[it].x * inv + b2.x, 0.f);
            float v1 = fmaxf(acc[it].y * inv + b2.y, 0.f);
            if (writeF32) {
                float2 o; o.x = v0; o.y = v1;
                *(float2*)(hout + (size_t)n * H + f) = o;
            }
            unsigned pk = (unsigned)f2b(v0) | ((unsigned)f2b(v1) << 16);
            *(unsigned*)(hbout + (size_t)n * H + f) = pk;
        }
    }
}

// ------------------------------------------------------------------ launch --
extern "C" void kernel_launch(void* const* d_in, const int* in_sizes, int n_in,
                              void* d_out, int out_size, void* d_ws, size_t ws_size,
                              hipStream_t stream) {
    const float* word_feats = (const float*)d_in[0];
    const float* boxes_norm = (const float*)d_in[1];
    const int*   edge_index = (const int*)d_in[2];
    const float* edge_cont  = (const float*)d_in[3];
    const int*   rel_ids    = (const int*)d_in[4];
    const float* rel_table  = (const float*)d_in[5];
    const float* Wl  = (const float*)d_in[6];
    const float* bl  = (const float*)d_in[7];
    const float* Wr  = (const float*)d_in[8];
    const float* br  = (const float*)d_in[9];
    const float* We  = (const float*)d_in[10];
    const float* att = (const float*)d_in[11];
    const float* bias_out = (const float*)d_in[12];
    float* h = (float*)d_out;

    const int N = in_sizes[0] / H;
    const int E = in_sizes[2] / 2;

    char* wsb = (char*)d_ws;
    size_t off_b = 0;
    auto alloc = [&](size_t bytes) -> void* {
        void* p = wsb + off_b;
        off_b += (bytes + 255) & ~(size_t)255;
        return p;
    };
    ushort_t* hb      = (ushort_t*)alloc((size_t)MPAD * H * 2);
    ushort_t* xl      = (ushort_t*)alloc((size_t)MPAD * H * 2);
    ushort_t* xr      = (ushort_t*)alloc((size_t)MPAD * H * 2);
    ushort_t* WT      = (ushort_t*)alloc((size_t)2 * 2 * H * H * 2); // [L][1536][768]
    float*    cpk     = (float*)alloc((size_t)E * 8 * 4);
    int*   counts  = (int*)alloc((size_t)(N + 1) * 4);
    int*   offsets = (int*)alloc((size_t)(N + 1) * 4);
    int*   cursor  = (int*)alloc((size_t)N * 4);
    int*   src_s   = (int*)alloc((size_t)E * 4);
    int*   order   = (int*)alloc((size_t)N * 4);
    int*   cellcnt = (int*)alloc((size_t)1024 * 4);
    int*   celloff = (int*)alloc((size_t)1025 * 4);
    int*   cellcur = (int*)alloc((size_t)1024 * 4);
    ushort_t* tabG  = (ushort_t*)alloc((size_t)2 * 13 * H * 2);

    (void)hipMemsetAsync(counts, 0, (size_t)(N + 1) * 4, stream);
    (void)hipMemsetAsync(cellcnt, 0, (size_t)1024 * 4, stream);
    (void)hipMemsetAsync(hb + (size_t)N * H, 0, (size_t)(MPAD - N) * H * 2, stream);

    // CSR (dst-sorted) with packed edge payloads
    count_kernel<<<(E + 255) / 256, 256, 0, stream>>>(edge_index + E, counts, E);
    scan_kernel<<<1, 1024, 0, stream>>>(counts, offsets, cursor, N);
    scatter_kernel<<<(E + 255) / 256, 256, 0, stream>>>(edge_index, edge_cont, rel_ids,
                                                        cursor, src_s, cpk, E);
    // spatial processing order
    cell_count_kernel<<<(N + 255) / 256, 256, 0, stream>>>(boxes_norm, cellcnt, N);
    scan_kernel<<<1, 1024, 0, stream>>>(cellcnt, celloff, cellcur, 1024);
    cell_scatter_kernel<<<(N + 255) / 256, 256, 0, stream>>>(boxes_norm, cellcur, order, N);

    posemb_kernel<<<(int)(((long long)N * H + 255) / 256), 256, 0, stream>>>(
        word_feats, boxes_norm, hb, N);
    tab_build_kernel<<<(2 * 13 * H + 255) / 256, 256, 0, stream>>>(We, rel_table, att, tabG);
    transpose_conv_kernel<<<dim3(H / 32, H / 32, 4), 256, 0, stream>>>(Wl, Wr, WT);

    dim3 ggrid(2 * H / 128, MPAD / 128);   // x=bn (12), y=bm (235)
    int gatgrid = (N + 4 * NPW - 1) / (4 * NPW);
    for (int l = 0; l < 2; ++l) {
        gemm_mfma<<<ggrid, 256, 0, stream>>>(hb, WT + (size_t)l * 2 * H * H,
                                             bl + (size_t)l * H, br + (size_t)l * H,
                                             xl, xr, N);
        gat_node_kernel<<<gatgrid, 256, 0, stream>>>(
            xl, xr, src_s, cpk, offsets, order,
            tabG + (size_t)l * 13 * H, bias_out + (size_t)l * H,
            h, hb, N, l == 1);
    }
}

// Round 12
// 815.349 us; speedup vs baseline: 1.3364x; 1.0528x over previous
//
#include <hip/hip_runtime.h>
#include <hip/hip_bf16.h>

#define H 768
#define MPAD 30080   // 235 * 128
#define CELLG 32     // spatial sort grid (32x32 = 1024 cells)

typedef unsigned short ushort_t;
typedef __attribute__((ext_vector_type(8))) short bf16x8;
typedef __attribute__((ext_vector_type(4))) float f32x4;
typedef __attribute__((ext_vector_type(2))) float f32x2;

__device__ __forceinline__ float b2f(ushort_t u) {
    unsigned x = ((unsigned)u) << 16;
    float f; __builtin_memcpy(&f, &x, 4); return f;
}
__device__ __forceinline__ ushort_t f2b(float f) {
    unsigned x; __builtin_memcpy(&x, &f, 4);
    unsigned r = (x + 0x7FFFu + ((x >> 16) & 1u)) >> 16;
    return (ushort_t)r;
}
// unpack 2 packed bf16 (lo,hi) -> f32x2
__device__ __forceinline__ f32x2 up2(unsigned u) {
    unsigned lo = u << 16, hi = u & 0xffff0000u;
    float flo, fhi;
    __builtin_memcpy(&flo, &lo, 4);
    __builtin_memcpy(&fhi, &hi, 4);
    f32x2 r;
    r.x = flo;
    r.y = fhi;
    return r;
}
// bijective XCD swizzle (m204): blocks bid%8==x all map to one contiguous
// work chunk, so each XCD's L2 sees a coherent region.
__device__ __forceinline__ int xcd_swz(int bid, int nwg) {
    int q = nwg >> 3, r = nwg & 7;
    int xcd = bid & 7, i = bid >> 3;
    return (xcd < r) ? (xcd * (q + 1) + i) : (r * (q + 1) + (xcd - r) * q + i);
}

// ---------------------------------------------------------------- pos emb ---
__global__ void posemb_kernel(const float* __restrict__ wf,
                              const float* __restrict__ bn,
                              ushort_t* __restrict__ hb, int N) {
    long long idx = (long long)blockIdx.x * blockDim.x + threadIdx.x;
    if (idx >= (long long)N * H) return;
    int n = (int)(idx / H);
    int f = (int)(idx % H);
    int c = f / 192;
    int j = f % 192;
    int k = (j < 96) ? j : j - 96;
    float invf = __expf(-((float)(2 * k) / 192.0f) * 9.210340371976184f);
    float v = bn[n * 4 + c] * invf;
    float pe = (j < 96) ? __sinf(v) : __cosf(v);
    hb[idx] = f2b(wf[idx] + pe);
}

// ---------------------------------------------------------------- CSR build --
__global__ void count_kernel(const int* __restrict__ dst, int* __restrict__ counts, int E) {
    int e = blockIdx.x * blockDim.x + threadIdx.x;
    if (e >= E) return;
    atomicAdd(&counts[dst[e]], 1);
}

__global__ void scan_kernel(const int* __restrict__ counts,
                            int* __restrict__ offsets,
                            int* __restrict__ cursor, int n) {
    __shared__ int partial[1024];
    int tid = threadIdx.x;
    int per = (n + 1023) / 1024;
    int base = tid * per;
    int sum = 0;
    for (int i = 0; i < per; ++i) {
        int idx = base + i;
        if (idx < n) sum += counts[idx];
    }
    partial[tid] = sum;
    __syncthreads();
    for (int offs = 1; offs < 1024; offs <<= 1) {
        int v = 0;
        if (tid >= offs) v = partial[tid - offs];
        __syncthreads();
        if (tid >= offs) partial[tid] += v;
        __syncthreads();
    }
    int running = (tid == 0) ? 0 : partial[tid - 1];
    for (int i = 0; i < per; ++i) {
        int idx = base + i;
        if (idx < n) {
            offsets[idx] = running;
            cursor[idx]  = running;
            running += counts[idx];
        }
    }
    if (tid == 0) offsets[n] = partial[1023];
}

// scatter + pack per-edge payload {cont[0..6], (float)rel} into dst-sorted order
__global__ void scatter_kernel(const int* __restrict__ ei,
                               const float* __restrict__ cont,
                               const int* __restrict__ rel,
                               int* __restrict__ cursor,
                               int* __restrict__ src_s,
                               float* __restrict__ cpk, int E) {
    int e = blockIdx.x * blockDim.x + threadIdx.x;
    if (e >= E) return;
    int s = ei[e], d = ei[E + e];
    int p = atomicAdd(&cursor[d], 1);
    src_s[p] = s;
    float c[8];
#pragma unroll
    for (int k = 0; k < 7; ++k) c[k] = cont[(size_t)e * 7 + k];
    c[7] = (float)rel[e];
    *(float4*)(cpk + (size_t)p * 8)     = make_float4(c[0], c[1], c[2], c[3]);
    *(float4*)(cpk + (size_t)p * 8 + 4) = make_float4(c[4], c[5], c[6], c[7]);
}

// ------------------------------------------------------ spatial node order ---
__device__ __forceinline__ int cell_of(const float* bn, int n) {
    float cx = (bn[n * 4 + 0] + bn[n * 4 + 2]) * 0.5f;   // [0,1]
    float cy = (bn[n * 4 + 1] + bn[n * 4 + 3]) * 0.5f;
    int ix = (int)(cx * CELLG); ix = ix < 0 ? 0 : (ix > CELLG - 1 ? CELLG - 1 : ix);
    int iy = (int)(cy * CELLG); iy = iy < 0 ? 0 : (iy > CELLG - 1 ? CELLG - 1 : iy);
    return iy * CELLG + ix;
}

__global__ void cell_count_kernel(const float* __restrict__ bn, int* __restrict__ cellcnt, int N) {
    int n = blockIdx.x * blockDim.x + threadIdx.x;
    if (n >= N) return;
    atomicAdd(&cellcnt[cell_of(bn, n)], 1);
}

__global__ void cell_scatter_kernel(const float* __restrict__ bn, int* __restrict__ cellcur,
                                    int* __restrict__ order, int N) {
    int n = blockIdx.x * blockDim.x + threadIdx.x;
    if (n >= N) return;
    int p = atomicAdd(&cellcur[cell_of(bn, n)], 1);
    order[p] = n;
}

// --------------------------------------------- bf16 fused table (13 x 768) ---
// rows 0..6 = We[l][0..6]; rows 7..11 = rel_table[r] @ We[l][7..22]; row 12 = att[l]
__global__ void tab_build_kernel(const float* __restrict__ We,
                                 const float* __restrict__ rel_table,
                                 const float* __restrict__ att,
                                 ushort_t* __restrict__ tabG) {
    int idx = blockIdx.x * blockDim.x + threadIdx.x;
    if (idx >= 2 * 13 * H) return;
    int f = idx % H;
    int row = (idx / H) % 13;
    int l = idx / (13 * H);
    const float* Wep = We + (size_t)l * 23 * H;
    float v;
    if (row < 7) {
        v = Wep[(size_t)row * H + f];
    } else if (row < 12) {
        int r = row - 7;
        v = 0.f;
#pragma unroll
        for (int k = 0; k < 16; ++k)
            v = fmaf(rel_table[r * 16 + k], Wep[(size_t)(7 + k) * H + f], v);
    } else {
        v = att[(size_t)l * H + f];
    }
    tabG[idx] = f2b(v);
}

// -------------------------------------------- weight transpose + bf16 cast ---
__global__ __launch_bounds__(256) void transpose_conv_kernel(
    const float* __restrict__ Wl, const float* __restrict__ Wr,
    ushort_t* __restrict__ WT) {
    __shared__ float t[32][33];
    int z = blockIdx.z;                 // 0:Wl0 1:Wl1 2:Wr0 3:Wr1
    const float* src = ((z < 2) ? Wl : Wr) + (size_t)(z & 1) * H * H;
    ushort_t*    dst = WT + (size_t)(z & 1) * 2 * H * H + ((z < 2) ? 0 : (size_t)H * H);
    int k0 = blockIdx.x * 32, n0 = blockIdx.y * 32;
    int tx = threadIdx.x & 31, ty = threadIdx.x >> 5;   // 32 x 8
#pragma unroll
    for (int r = 0; r < 4; ++r)
        t[ty + 8 * r][tx] = src[(size_t)(k0 + ty + 8 * r) * H + n0 + tx];
    __syncthreads();
#pragma unroll
    for (int r = 0; r < 4; ++r)
        dst[(size_t)(n0 + ty + 8 * r) * H + k0 + tx] = f2b(t[tx][ty + 8 * r]);
}

// ------------------------------------------------------------ MFMA GEMM -----
// 1D grid of 2820 blocks, XCD-swizzled bm-major: all 12 bn-blocks of one
// A-panel land on one XCD -> A fetched ~once device-wide.
__global__ __launch_bounds__(256) void gemm_mfma(
    const ushort_t* __restrict__ A,
    const ushort_t* __restrict__ Bt,   // [1536][768]
    const float* __restrict__ bl, const float* __restrict__ br,
    ushort_t* __restrict__ xl, ushort_t* __restrict__ xr, int M) {
    __shared__ __align__(16) ushort_t smem[8192];   // 16 KB: sA 8KB | sB 8KB
    ushort_t* sA = smem;
    ushort_t* sB = smem + 4096;
    int tid = threadIdx.x;
    int wave = tid >> 6, lane = tid & 63;
    int wg = xcd_swz(blockIdx.x, gridDim.x);
    int bn = (wg % 12) * 128;
    int bm = (wg / 12) * 128;
    int wr = wave >> 1, wc = wave & 1;
    f32x4 acc[4][4] = {};

    int sr = lane >> 2;
    int sk = (lane & 3) * 8;
    const ushort_t* gA = A  + (size_t)(bm + sr) * H + sk;
    const ushort_t* gB = Bt + (size_t)(bn + sr) * H + sk;
    int fr = lane & 15, fq = lane >> 4;

    for (int k0 = 0; k0 < H; k0 += 32) {
#pragma unroll
        for (int i = 0; i < 2; ++i) {
            int q = wave * 2 + i;
            __builtin_amdgcn_global_load_lds(
                (const __attribute__((address_space(1))) unsigned*)(gA + (size_t)(16 * q) * H + k0),
                (__attribute__((address_space(3))) unsigned*)(sA + q * 512), 16, 0, 0);
            __builtin_amdgcn_global_load_lds(
                (const __attribute__((address_space(1))) unsigned*)(gB + (size_t)(16 * q) * H + k0),
                (__attribute__((address_space(3))) unsigned*)(sB + q * 512), 16, 0, 0);
        }
        __syncthreads();
        bf16x8 a[4], b[4];
#pragma unroll
        for (int m = 0; m < 4; ++m)
            a[m] = *(const bf16x8*)&sA[(wr * 64 + m * 16 + fr) * 32 + fq * 8];
#pragma unroll
        for (int n = 0; n < 4; ++n)
            b[n] = *(const bf16x8*)&sB[(wc * 64 + n * 16 + fr) * 32 + fq * 8];
#pragma unroll
        for (int m = 0; m < 4; ++m)
#pragma unroll
            for (int n = 0; n < 4; ++n)
                acc[m][n] = __builtin_amdgcn_mfma_f32_16x16x32_bf16(a[m], b[n], acc[m][n], 0, 0, 0);
        __syncthreads();
    }

    const bool left = (bn < H);
    ushort_t* Cp = left ? xl : xr;
    const float* bias = left ? bl : br;
    int cb = bn - (left ? 0 : H);
    float bv[4];
#pragma unroll
    for (int n = 0; n < 4; ++n) bv[n] = bias[cb + wc * 64 + n * 16 + fr];

    ushort_t* sC = smem;
#pragma unroll
    for (int hh = 0; hh < 2; ++hh) {
        if (wr == hh) {
#pragma unroll
            for (int m = 0; m < 4; ++m)
#pragma unroll
                for (int n = 0; n < 4; ++n) {
                    int col = wc * 64 + n * 16 + fr;
#pragma unroll
                    for (int j = 0; j < 4; ++j) {
                        int rloc = m * 16 + fq * 4 + j;
                        sC[rloc * 128 + col] = f2b(acc[m][n][j] + bv[n]);
                    }
                }
        }
        __syncthreads();
        int rowg0 = bm + hh * 64;
#pragma unroll
        for (int i = 0; i < 4; ++i) {
            int t16 = i * 256 + tid;
            int rloc = t16 >> 4;
            int cchunk = t16 & 15;
            int rowg = rowg0 + rloc;
            if (rowg < M)
                *(uint4*)(Cp + (size_t)rowg * H + cb + cchunk * 8) =
                    *(const uint4*)&sC[rloc * 128 + cchunk * 8];
        }
        __syncthreads();
    }
}

// ---------------------------------------- fused GATv2 per-node edge phase ---
// XCD-swizzled block->node-range; bf16 tables in LDS; uint2 (8B/lane) gathers;
// 2-edge pipelined branchless online softmax. Feature map: f = lane*4+seg*256.
#define NPW 4
__global__ __launch_bounds__(256) void gat_node_kernel(
    const ushort_t* __restrict__ xl, const ushort_t* __restrict__ xr,
    const int* __restrict__ src_s, const float* __restrict__ cpk,
    const int* __restrict__ off, const int* __restrict__ order,
    const ushort_t* __restrict__ tabG,   // 13*768 bf16 for this layer
    const float* __restrict__ bias,
    float* __restrict__ hout, ushort_t* __restrict__ hbout,
    int N, int writeF32) {
    __shared__ ushort_t sTab[13 * H];
    for (int i = threadIdx.x; i < 13 * H / 2; i += 256)
        ((unsigned*)sTab)[i] = ((const unsigned*)tabG)[i];
    __syncthreads();

    int wg = xcd_swz(blockIdx.x, gridDim.x);
    int wave = threadIdx.x >> 6;
    int lane = threadIdx.x & 63;
    int gw = wg * 4 + wave;
    int fb = lane * 4;   // feature base within a 256-chunk

    for (int j = 0; j < NPW; ++j) {
        int oi = gw * NPW + j;
        if (oi >= N) return;
        int n = order[oi];
        int s0 = off[n], s1 = off[n + 1];

        // xr row: 12 features/lane at f = fb + seg*256 + {0..3}
        f32x2 xrv[3][2];
#pragma unroll
        for (int seg = 0; seg < 3; ++seg) {
            uint2 u = *(const uint2*)(xr + (size_t)n * H + fb + seg * 256);
            xrv[seg][0] = up2(u.x);
            xrv[seg][1] = up2(u.y);
        }

        float m_run = -1e30f, s_run = 0.f;
        f32x2 acc[3][2] = {};
        int s = s0;

        for (; s + 2 <= s1; s += 2) {
            int srcA = src_s[s], srcB = src_s[s + 1];
            float4 ca0 = *(const float4*)(cpk + (size_t)s * 8);
            float4 ca1 = *(const float4*)(cpk + (size_t)s * 8 + 4);
            float4 cb0 = *(const float4*)(cpk + (size_t)(s + 1) * 8);
            float4 cb1 = *(const float4*)(cpk + (size_t)(s + 1) * 8 + 4);
            int rA = (int)ca1.w, rB = (int)cb1.w;
            const ushort_t* pa = xl + (size_t)srcA * H;
            const ushort_t* pb = xl + (size_t)srcB * H;
            float cA[7] = {ca0.x, ca0.y, ca0.z, ca0.w, ca1.x, ca1.y, ca1.z};
            float cB[7] = {cb0.x, cb0.y, cb0.z, cb0.w, cb1.x, cb1.y, cb1.z};

            f32x2 xa[3][2], xb[3][2];
#pragma unroll
            for (int seg = 0; seg < 3; ++seg) {
                uint2 ua = *(const uint2*)(pa + fb + seg * 256);
                uint2 ub = *(const uint2*)(pb + fb + seg * 256);
                xa[seg][0] = up2(ua.x); xa[seg][1] = up2(ua.y);
                xb[seg][0] = up2(ub.x); xb[seg][1] = up2(ub.y);
            }

            f32x2 sa = {0.f, 0.f}, sb = {0.f, 0.f};
#pragma unroll
            for (int seg = 0; seg < 3; ++seg) {
                int f = fb + seg * 256;
                uint2 uea = *(const uint2*)(sTab + (7 + rA) * H + f);
                uint2 ueb = *(const uint2*)(sTab + (7 + rB) * H + f);
                f32x2 eA[2] = { up2(uea.x), up2(uea.y) };
                f32x2 eB[2] = { up2(ueb.x), up2(ueb.y) };
#pragma unroll
                for (int k = 0; k < 7; ++k) {
                    uint2 uw = *(const uint2*)(sTab + k * H + f);
                    f32x2 w0 = up2(uw.x), w1 = up2(uw.y);
                    eA[0] = w0 * cA[k] + eA[0];
                    eA[1] = w1 * cA[k] + eA[1];
                    eB[0] = w0 * cB[k] + eB[0];
                    eB[1] = w1 * cB[k] + eB[1];
                }
                uint2 uav = *(const uint2*)(sTab + 12 * H + f);
                f32x2 av0 = up2(uav.x), av1 = up2(uav.y);
#pragma unroll
                for (int hh = 0; hh < 2; ++hh) {
                    f32x2 mA = xa[seg][hh] + xrv[seg][hh] + eA[hh];
                    f32x2 mB = xb[seg][hh] + xrv[seg][hh] + eB[hh];
                    f32x2 lA, lB;
                    lA.x = fmaxf(mA.x, 0.f) + 0.2f * fminf(mA.x, 0.f);
                    lA.y = fmaxf(mA.y, 0.f) + 0.2f * fminf(mA.y, 0.f);
                    lB.x = fmaxf(mB.x, 0.f) + 0.2f * fminf(mB.x, 0.f);
                    lB.y = fmaxf(mB.y, 0.f) + 0.2f * fminf(mB.y, 0.f);
                    f32x2 av = hh ? av1 : av0;
                    sa = lA * av + sa;
                    sb = lB * av + sb;
                }
            }
            float pA = sa.x + sa.y, pB = sb.x + sb.y;
#pragma unroll
            for (int o = 32; o; o >>= 1) {
                pA += __shfl_xor(pA, o);
                pB += __shfl_xor(pB, o);
            }
            float mnew = fmaxf(m_run, fmaxf(pA, pB));
            float scale = __expf(m_run - mnew);
            float wA = __expf(pA - mnew);
            float wB = __expf(pB - mnew);
            s_run = s_run * scale + wA + wB;
#pragma unroll
            for (int seg = 0; seg < 3; ++seg)
#pragma unroll
                for (int hh = 0; hh < 2; ++hh)
                    acc[seg][hh] = acc[seg][hh] * scale + xa[seg][hh] * wA + xb[seg][hh] * wB;
            m_run = mnew;
        }

        if (s < s1) {   // tail edge
            int srcA = src_s[s];
            float4 ca0 = *(const float4*)(cpk + (size_t)s * 8);
            float4 ca1 = *(const float4*)(cpk + (size_t)s * 8 + 4);
            int rA = (int)ca1.w;
            const ushort_t* pa = xl + (size_t)srcA * H;
            float cA[7] = {ca0.x, ca0.y, ca0.z, ca0.w, ca1.x, ca1.y, ca1.z};
            f32x2 xa[3][2];
#pragma unroll
            for (int seg = 0; seg < 3; ++seg) {
                uint2 ua = *(const uint2*)(pa + fb + seg * 256);
                xa[seg][0] = up2(ua.x); xa[seg][1] = up2(ua.y);
            }
            f32x2 sa = {0.f, 0.f};
#pragma unroll
            for (int seg = 0; seg < 3; ++seg) {
                int f = fb + seg * 256;
                uint2 uea = *(const uint2*)(sTab + (7 + rA) * H + f);
                f32x2 eA[2] = { up2(uea.x), up2(uea.y) };
#pragma unroll
                for (int k = 0; k < 7; ++k) {
                    uint2 uw = *(const uint2*)(sTab + k * H + f);
                    eA[0] = up2(uw.x) * cA[k] + eA[0];
                    eA[1] = up2(uw.y) * cA[k] + eA[1];
                }
                uint2 uav = *(const uint2*)(sTab + 12 * H + f);
#pragma unroll
                for (int hh = 0; hh < 2; ++hh) {
                    f32x2 mA = xa[seg][hh] + xrv[seg][hh] + eA[hh];
                    f32x2 lA;
                    lA.x = fmaxf(mA.x, 0.f) + 0.2f * fminf(mA.x, 0.f);
                    lA.y = fmaxf(mA.y, 0.f) + 0.2f * fminf(mA.y, 0.f);
                    sa = lA * up2(hh ? uav.y : uav.x) + sa;
                }
            }
            float pA = sa.x + sa.y;
#pragma unroll
            for (int o = 32; o; o >>= 1) pA += __shfl_xor(pA, o);
            float mnew = fmaxf(m_run, pA);
            float scale = __expf(m_run - mnew);
            float wA = __expf(pA - mnew);
            s_run = s_run * scale + wA;
#pragma unroll
            for (int seg = 0; seg < 3; ++seg)
#pragma unroll
                for (int hh = 0; hh < 2; ++hh)
                    acc[seg][hh] = acc[seg][hh] * scale + xa[seg][hh] * wA;
            m_run = mnew;
        }

        float inv = (s_run > 0.f) ? 1.f / (s_run + 1e-16f) : 0.f;
#pragma unroll
        for (int seg = 0; seg < 3; ++seg) {
            int f = fb + seg * 256;
            float4 b4 = *(const float4*)&bias[f];
            float v0 = fmaxf(acc[seg][0].x * inv + b4.x, 0.f);
            float v1 = fmaxf(acc[seg][0].y * inv + b4.y, 0.f);
            float v2 = fmaxf(acc[seg][1].x * inv + b4.z, 0.f);
            float v3 = fmaxf(acc[seg][1].y * inv + b4.w, 0.f);
            if (writeF32) {
                float4 o; o.x = v0; o.y = v1; o.z = v2; o.w = v3;
                *(float4*)(hout + (size_t)n * H + f) = o;
            }
            uint2 pk;
            pk.x = (unsigned)f2b(v0) | ((unsigned)f2b(v1) << 16);
            pk.y = (unsigned)f2b(v2) | ((unsigned)f2b(v3) << 16);
            *(uint2*)(hbout + (size_t)n * H + f) = pk;
        }
    }
}

// ------------------------------------------------------------------ launch --
extern "C" void kernel_launch(void* const* d_in, const int* in_sizes, int n_in,
                              void* d_out, int out_size, void* d_ws, size_t ws_size,
                              hipStream_t stream) {
    const float* word_feats = (const float*)d_in[0];
    const float* boxes_norm = (const float*)d_in[1];
    const int*   edge_index = (const int*)d_in[2];
    const float* edge_cont  = (const float*)d_in[3];
    const int*   rel_ids    = (const int*)d_in[4];
    const float* rel_table  = (const float*)d_in[5];
    const float* Wl  = (const float*)d_in[6];
    const float* bl  = (const float*)d_in[7];
    const float* Wr  = (const float*)d_in[8];
    const float* br  = (const float*)d_in[9];
    const float* We  = (const float*)d_in[10];
    const float* att = (const float*)d_in[11];
    const float* bias_out = (const float*)d_in[12];
    float* h = (float*)d_out;

    const int N = in_sizes[0] / H;
    const int E = in_sizes[2] / 2;

    char* wsb = (char*)d_ws;
    size_t off_b = 0;
    auto alloc = [&](size_t bytes) -> void* {
        void* p = wsb + off_b;
        off_b += (bytes + 255) & ~(size_t)255;
        return p;
    };
    ushort_t* hb      = (ushort_t*)alloc((size_t)MPAD * H * 2);
    ushort_t* xl      = (ushort_t*)alloc((size_t)MPAD * H * 2);
    ushort_t* xr      = (ushort_t*)alloc((size_t)MPAD * H * 2);
    ushort_t* WT      = (ushort_t*)alloc((size_t)2 * 2 * H * H * 2); // [L][1536][768]
    float*    cpk     = (float*)alloc((size_t)E * 8 * 4);
    int*   counts  = (int*)alloc((size_t)(N + 1) * 4);
    int*   offsets = (int*)alloc((size_t)(N + 1) * 4);
    int*   cursor  = (int*)alloc((size_t)N * 4);
    int*   src_s   = (int*)alloc((size_t)E * 4);
    int*   order   = (int*)alloc((size_t)N * 4);
    int*   cellcnt = (int*)alloc((size_t)1024 * 4);
    int*   celloff = (int*)alloc((size_t)1025 * 4);
    int*   cellcur = (int*)alloc((size_t)1024 * 4);
    ushort_t* tabG  = (ushort_t*)alloc((size_t)2 * 13 * H * 2);

    (void)hipMemsetAsync(counts, 0, (size_t)(N + 1) * 4, stream);
    (void)hipMemsetAsync(cellcnt, 0, (size_t)1024 * 4, stream);
    (void)hipMemsetAsync(hb + (size_t)N * H, 0, (size_t)(MPAD - N) * H * 2, stream);

    // CSR (dst-sorted) with packed edge payloads
    count_kernel<<<(E + 255) / 256, 256, 0, stream>>>(edge_index + E, counts, E);
    scan_kernel<<<1, 1024, 0, stream>>>(counts, offsets, cursor, N);
    scatter_kernel<<<(E + 255) / 256, 256, 0, stream>>>(edge_index, edge_cont, rel_ids,
                                                        cursor, src_s, cpk, E);
    // spatial processing order
    cell_count_kernel<<<(N + 255) / 256, 256, 0, stream>>>(boxes_norm, cellcnt, N);
    scan_kernel<<<1, 1024, 0, stream>>>(cellcnt, celloff, cellcur, 1024);
    cell_scatter_kernel<<<(N + 255) / 256, 256, 0, stream>>>(boxes_norm, cellcur, order, N);

    posemb_kernel<<<(int)(((long long)N * H + 255) / 256), 256, 0, stream>>>(
        word_feats, boxes_norm, hb, N);
    tab_build_kernel<<<(2 * 13 * H + 255) / 256, 256, 0, stream>>>(We, rel_table, att, tabG);
    transpose_conv_kernel<<<dim3(H / 32, H / 32, 4), 256, 0, stream>>>(Wl, Wr, WT);

    int ggrid = (2 * H / 128) * (MPAD / 128);   // 12 * 235 = 2820, 1D swizzled
    int gatgrid = (N + 4 * NPW - 1) / (4 * NPW);
    for (int l = 0; l < 2; ++l) {
        gemm_mfma<<<ggrid, 256, 0, stream>>>(hb, WT + (size_t)l * 2 * H * H,
                                             bl + (size_t)l * H, br + (size_t)l * H,
                                             xl, xr, N);
        gat_node_kernel<<<gatgrid, 256, 0, stream>>>(
            xl, xr, src_s, cpk, offsets, order,
            tabG + (size_t)l * 13 * H, bias_out + (size_t)l * H,
            h, hb, N, l == 1);
    }
}